// Round 12
// baseline (301.567 us; speedup 1.0000x reference)
//
#include <hip/hip_runtime.h>
#include <math.h>

#define M_TOK 4096           // B*S
#define HID   2048
#define NEXP  8
#define CAP   1536
#define DISP_ELEMS 50331648ull   // 4096*8*1536
#define NTOT  5120               // 1024 + 2048 + 2048 (concat N)
#define ZTOT4 25165824ull        // (2*DISP_ELEMS)/4 float4s

typedef __attribute__((ext_vector_type(8))) short bf16x8;
typedef __attribute__((ext_vector_type(4))) float f32x4;

__device__ __forceinline__ unsigned short f2bf(float f) {
  unsigned u = __float_as_uint(f);
  unsigned r = u + 0x7FFFu + ((u >> 16) & 1u);   // RNE (finite inputs)
  return (unsigned short)(r >> 16);
}
__device__ __forceinline__ float bf2f(unsigned short h) {
  return __uint_as_float(((unsigned)h) << 16);
}

__device__ __forceinline__ void gload16(const void* g, void* l) {
  __builtin_amdgcn_global_load_lds(
      (const __attribute__((address_space(1))) void*)g,
      (__attribute__((address_space(3))) void*)l, 16, 0, 0);
}
__device__ __forceinline__ bf16x8 ldsread(const unsigned short* p) {
  return *reinterpret_cast<const bf16x8*>(p);
}

// ---------------------------------------------------------------------------
// x (fp32 [M][K]) -> x_hi, x_lo (bf16 [M][K])   (r10-proven)
// ---------------------------------------------------------------------------
__global__ __launch_bounds__(256)
void convert_x_k(const float* __restrict__ x, unsigned short* __restrict__ xh,
                 unsigned short* __restrict__ xl) {
  size_t i = ((size_t)blockIdx.x * 256 + threadIdx.x) * 4;
  float4 v = *reinterpret_cast<const float4*>(&x[i]);
  float f[4] = {v.x, v.y, v.z, v.w};
  unsigned short hh[4], ll[4];
#pragma unroll
  for (int j = 0; j < 4; ++j) {
    hh[j] = f2bf(f[j]);
    ll[j] = f2bf(f[j] - bf2f(hh[j]));
  }
  uint2 ph, pl;
  ph.x = hh[0] | ((unsigned)hh[1] << 16); ph.y = hh[2] | ((unsigned)hh[3] << 16);
  pl.x = ll[0] | ((unsigned)ll[1] << 16); pl.y = ll[2] | ((unsigned)ll[3] << 16);
  *reinterpret_cast<uint2*>(&xh[i]) = ph;
  *reinterpret_cast<uint2*>(&xl[i]) = pl;
}

// ---------------------------------------------------------------------------
// All three W (fp32 [K=2048][N]) -> W^T hi/lo (bf16 [5120][2048]) (r10-proven)
// grid.x: 0..31 -> Wi1 (N=1024), 32..95 -> Wr1, 96..159 -> Wu1. grid.y = k0/32.
// ---------------------------------------------------------------------------
__global__ __launch_bounds__(256)
void convert_wT_k(const float* __restrict__ Wi1, const float* __restrict__ Wr1,
                  const float* __restrict__ Wu1,
                  unsigned short* __restrict__ wTh,
                  unsigned short* __restrict__ wTl) {
  __shared__ float tile[32][33];
  const int bx = blockIdx.x;
  const float* W; int N, rowOff, nb;
  if (bx < 32)      { W = Wi1; N = 1024; rowOff = 0;    nb = bx; }
  else if (bx < 96) { W = Wr1; N = 2048; rowOff = 1024; nb = bx - 32; }
  else              { W = Wu1; N = 2048; rowOff = 3072; nb = bx - 96; }
  const int k0 = blockIdx.y * 32;
  const int n0 = nb * 32;
  const int tid = threadIdx.x;
  {
    int r = tid >> 3, c4 = (tid & 7) * 4;
    float4 v = *reinterpret_cast<const float4*>(&W[(size_t)(k0 + r) * N + n0 + c4]);
    tile[r][c4 + 0] = v.x; tile[r][c4 + 1] = v.y;
    tile[r][c4 + 2] = v.z; tile[r][c4 + 3] = v.w;
  }
  __syncthreads();
  int n = tid >> 3, kc = (tid & 7) * 4;
  unsigned short hh[4], ll[4];
#pragma unroll
  for (int j = 0; j < 4; ++j) {
    float f = tile[kc + j][n];
    hh[j] = f2bf(f);
    ll[j] = f2bf(f - bf2f(hh[j]));
  }
  size_t o = (size_t)(rowOff + n0 + n) * HID + k0 + kc;
  uint2 ph, pl;
  ph.x = hh[0] | ((unsigned)hh[1] << 16); ph.y = hh[2] | ((unsigned)hh[3] << 16);
  pl.x = ll[0] | ((unsigned)ll[1] << 16); pl.y = ll[2] | ((unsigned)ll[3] << 16);
  *reinterpret_cast<uint2*>(&wTh[o]) = ph;
  *reinterpret_cast<uint2*>(&wTl[o]) = pl;
}

// ---------------------------------------------------------------------------
// Split-bf16 GEMM v3 (r11-proven, 248 us): 2 blocks/CU cross-block pipelining.
// BM=128, BN=320, BK=32 -> grid 512 = exactly 2 blocks/CU, one generation.
// 512 thr (8 waves 2M x 4N), wave-tile 64x80. Single 56 KB LDS buffer.
// Zerofill nt-stores issued at TOP of loop (retire under compute; they count
// against vmcnt, so early issue keeps next tile's vmcnt(0) load-only).
// ---------------------------------------------------------------------------
__global__ __launch_bounds__(512, 4)
void gemm_split_k(const unsigned short* __restrict__ Ahg,
                  const unsigned short* __restrict__ Alg,
                  const unsigned short* __restrict__ Bhg,
                  const unsigned short* __restrict__ Blg,
                  const float* __restrict__ bi1, const float* __restrict__ br1,
                  const float* __restrict__ bu1, float* __restrict__ h_i,
                  float* __restrict__ h_r, float* __restrict__ h_u,
                  float* __restrict__ dzero) {
  // sections (shorts): Ah@0(4096) Al@4096 Bh@8192(10240) Bl@18432 -> 28672
  __shared__ unsigned short lds[28672];          // 56 KB single buffer
  const int bid  = blockIdx.x;
  const int tid  = threadIdx.x;
  const int lane = tid & 63;
  const int wave = tid >> 6;
  const int lr   = lane & 15;
  const int slot = lane >> 4;

  // XCD swizzle: xcd = bid&7 owns nt pair {2x, 2x+1} -> B panel L2-resident
  const int idx = bid >> 3;                      // 0..63
  const int nt  = (bid & 7) * 2 + (idx >> 5);    // 0..15
  const int mt  = idx & 31;                      // 0..31
  const int row0  = mt * 128;
  const int bcol0 = nt * 320;

  // ---- staging map: 7 x 16B chunks/thread/K-tile (56KB)
  const unsigned short* gsrc[7];
#pragma unroll
  for (int j = 0; j < 7; ++j) {
    int cb = wave * 7 + j;
    int c  = cb * 64 + lane;
    const unsigned short* base;
    int sidx, rowg;
    if (cb < 8)       { sidx = c;        base = Ahg; rowg = row0  + (sidx >> 2); }
    else if (cb < 16) { sidx = c - 512;  base = Alg; rowg = row0  + (sidx >> 2); }
    else if (cb < 36) { sidx = c - 1024; base = Bhg; rowg = bcol0 + (sidx >> 2); }
    else              { sidx = c - 2304; base = Blg; rowg = bcol0 + (sidx >> 2); }
    int q  = sidx & 3;
    int qs = q ^ (((sidx >> 2) >> 1) & 3);       // pre-swizzled source slot
    gsrc[j] = base + (size_t)rowg * HID + qs * 8;
  }
  const int ldsbase = (wave * 7) * 512 + lane * 8;

  // ---- ds_read offsets (swizzled, conflict-free per r3 PMC)
  int aoff[4], boff[5];
#pragma unroll
  for (int m = 0; m < 4; ++m) {
    int ra = (wave >> 2) * 64 + m * 16 + lr;
    aoff[m] = ra * 32 + (slot ^ ((ra >> 1) & 3)) * 8;
  }
#pragma unroll
  for (int n = 0; n < 5; ++n) {
    int rb = (wave & 3) * 80 + n * 16 + lr;
    boff[n] = rb * 32 + (slot ^ ((rb >> 1) & 3)) * 8;
  }

  f32x4 acc[4][5];
#pragma unroll
  for (int m = 0; m < 4; ++m)
#pragma unroll
    for (int n = 0; n < 5; ++n) acc[m][n] = (f32x4){0.f, 0.f, 0.f, 0.f};

  auto stage = [&](int kt) {
#pragma unroll
    for (int j = 0; j < 7; ++j)
      gload16(gsrc[j] + kt * 32, &lds[ldsbase + j * 512]);
  };

  const bool dz = (dzero != nullptr);
  f32x4* d4 = (f32x4*)dzero;
  const f32x4 zv = (f32x4){0.f, 0.f, 0.f, 0.f};
  const size_t zbase = (size_t)bid * 49152 + tid;

  stage(0);                                      // prologue

#pragma unroll 1
  for (int t = 0; t < 64; ++t) {
    asm volatile("s_waitcnt vmcnt(0)" ::: "memory");  // tile t landed
    __builtin_amdgcn_s_barrier();
    __builtin_amdgcn_sched_barrier(0);

    // ---- zerofill issued early: retires under the compute below
    if (dz) {
      int start = (3 * t) >> 1;
      int cnt   = ((3 * (t + 1)) >> 1) - start;
      __builtin_nontemporal_store(zv, d4 + zbase + (size_t)start * 512);
      if (cnt == 2)
        __builtin_nontemporal_store(zv, d4 + zbase + (size_t)(start + 1) * 512);
    }

    // ---- 3-pass compute (one B-frag set live at a time -> low VGPR)
    bf16x8 bv[5];
#pragma unroll
    for (int n = 0; n < 5; ++n) bv[n] = ldsread(&lds[8192 + boff[n]]);   // Bh
#pragma unroll
    for (int m = 0; m < 4; ++m) {
      bf16x8 a = ldsread(&lds[aoff[m]]);                                 // Ah
      __builtin_amdgcn_s_setprio(1);
#pragma unroll
      for (int n = 0; n < 5; ++n)
        acc[m][n] = __builtin_amdgcn_mfma_f32_16x16x32_bf16(a, bv[n], acc[m][n], 0, 0, 0);
      __builtin_amdgcn_s_setprio(0);
    }
#pragma unroll
    for (int n = 0; n < 5; ++n) bv[n] = ldsread(&lds[18432 + boff[n]]);  // Bl
#pragma unroll
    for (int m = 0; m < 4; ++m) {
      bf16x8 a = ldsread(&lds[aoff[m]]);                                 // Ah
      __builtin_amdgcn_s_setprio(1);
#pragma unroll
      for (int n = 0; n < 5; ++n)
        acc[m][n] = __builtin_amdgcn_mfma_f32_16x16x32_bf16(a, bv[n], acc[m][n], 0, 0, 0);
      __builtin_amdgcn_s_setprio(0);
    }
#pragma unroll
    for (int n = 0; n < 5; ++n) bv[n] = ldsread(&lds[8192 + boff[n]]);   // Bh
#pragma unroll
    for (int m = 0; m < 4; ++m) {
      bf16x8 a = ldsread(&lds[4096 + aoff[m]]);                          // Al
      __builtin_amdgcn_s_setprio(1);
#pragma unroll
      for (int n = 0; n < 5; ++n)
        acc[m][n] = __builtin_amdgcn_mfma_f32_16x16x32_bf16(a, bv[n], acc[m][n], 0, 0, 0);
      __builtin_amdgcn_s_setprio(0);
    }

    __builtin_amdgcn_s_barrier();                // all reads of buffer done
    if (t < 63) stage(t + 1);                    // refill freed buffer
  }

  // ---- epilogue: bias + relu + store
#pragma unroll
  for (int n = 0; n < 5; ++n) {
    int cbase = nt * 320 + (wave & 3) * 80 + n * 16;
    float* C; const float* bias; int ldc, coff;
    if (cbase < 1024)      { C = h_i; bias = bi1; ldc = 1024; coff = 0; }
    else if (cbase < 3072) { C = h_r; bias = br1; ldc = 2048; coff = 1024; }
    else                   { C = h_u; bias = bu1; ldc = 2048; coff = 3072; }
    int cl = cbase - coff + lr;
    float bn = bias[cl];
#pragma unroll
    for (int m = 0; m < 4; ++m) {
      int rbase = row0 + (wave >> 2) * 64 + m * 16 + slot * 4;
#pragma unroll
      for (int j = 0; j < 4; ++j)
        C[(size_t)(rbase + j) * ldc + cl] = fmaxf(acc[m][n][j] + bn, 0.f);
    }
  }
}

// ---------------------------------------------------------------------------
// Router v2 (r10-proven): 256 blocks x 16 tokens, W2 staged once into LDS.
// ---------------------------------------------------------------------------
__global__ __launch_bounds__(256)
void router_k(const float* __restrict__ h_i, const float* __restrict__ h_r,
              const float* __restrict__ h_u,
              const float* __restrict__ Wi2, const float* __restrict__ bi2,
              const float* __restrict__ Wr2, const float* __restrict__ br2,
              const float* __restrict__ Wu2, const float* __restrict__ bu2,
              float* __restrict__ router_probs, float* __restrict__ importance,
              int* __restrict__ expert_used) {
  __shared__ float wr[18432];   // 2048 rows x 9 (8 used + pad)
  __shared__ float wu[18432];
  __shared__ float wi[1024];
  const int tid = threadIdx.x;

  for (int idx = tid; idx < 16384; idx += 256)
    wr[(idx >> 3) * 9 + (idx & 7)] = Wr2[idx];
  for (int idx = tid; idx < 16384; idx += 256)
    wu[(idx >> 3) * 9 + (idx & 7)] = Wu2[idx];
  for (int idx = tid; idx < 1024; idx += 256) wi[idx] = Wi2[idx];
  __syncthreads();

  const int w = tid >> 6, l = tid & 63;
  const float bi2v = bi2[0];

#pragma unroll 1
  for (int tt = 0; tt < 4; ++tt) {
    const int t = blockIdx.x * 16 + tt * 4 + w;
    float acc[17];
#pragma unroll
    for (int k = 0; k < 17; ++k) acc[k] = 0.f;

    const float* hi = &h_i[(size_t)t * 1024];
    const float* hr = &h_r[(size_t)t * 2048];
    const float* hu = &h_u[(size_t)t * 2048];
#pragma unroll 4
    for (int j = 0; j < 16; ++j) {
      int k = j * 64 + l;
      acc[0] = fmaf(hi[k], wi[k], acc[0]);
    }
#pragma unroll 4
    for (int j = 0; j < 32; ++j) {
      int k = j * 64 + l;
      float hrv = hr[k], huv = hu[k];
      const float* wrr = &wr[k * 9];
      const float* wuu = &wu[k * 9];
#pragma unroll
      for (int e = 0; e < 8; ++e) {
        acc[1 + e] = fmaf(hrv, wrr[e], acc[1 + e]);
        acc[9 + e] = fmaf(huv, wuu[e], acc[9 + e]);
      }
    }
#pragma unroll
    for (int k = 0; k < 17; ++k) {
      float v = acc[k];
      v += __shfl_xor(v, 1);  v += __shfl_xor(v, 2);  v += __shfl_xor(v, 4);
      v += __shfl_xor(v, 8);  v += __shfl_xor(v, 16); v += __shfl_xor(v, 32);
      acc[k] = v;
    }
    if (l == 0) {
      float imp = 1.f / (1.f + expf(-(acc[0] + bi2v)));
      importance[t] = imp;
      bool useImp = imp > 0.5f;
      float logits[8];
#pragma unroll
      for (int e = 0; e < 8; ++e)
        logits[e] = useImp ? (acc[1 + e] + br2[e]) : (acc[9 + e] + bu2[e]);
      float mx = logits[0];
#pragma unroll
      for (int e = 1; e < 8; ++e) mx = fmaxf(mx, logits[e]);
      float ex[8], sum = 0.f;
#pragma unroll
      for (int e = 0; e < 8; ++e) { ex[e] = expf(logits[e] - mx); sum += ex[e]; }
      float p[8];
#pragma unroll
      for (int e = 0; e < 8; ++e) p[e] = ex[e] / sum;
#pragma unroll
      for (int e = 0; e < 8; ++e) router_probs[(size_t)t * 8 + e] = p[e];
      int e1 = 0; float p1 = p[0];
#pragma unroll
      for (int e = 1; e < 8; ++e) if (p[e] > p1) { p1 = p[e]; e1 = e; }
      expert_used[e1] = 1;   // benign race: all writers store 1
    }
  }
}

// ---------------------------------------------------------------------------
// Scatter + aux partial reduction. 16 blocks x 256 thr.
// ---------------------------------------------------------------------------
__global__ __launch_bounds__(256)
void scatter_aux_k(const float* __restrict__ router_probs,
                   const int* __restrict__ expert_used,
                   const float* __restrict__ importance,
                   float* __restrict__ disp, float* __restrict__ comb,
                   float* __restrict__ partials) {
  const int tid = threadIdx.x;
  const int t = blockIdx.x * 256 + tid;
  float4 a = *reinterpret_cast<const float4*>(&router_probs[(size_t)t * 8]);
  float4 b = *reinterpret_cast<const float4*>(&router_probs[(size_t)t * 8 + 4]);
  float p[8] = {a.x, a.y, a.z, a.w, b.x, b.y, b.z, b.w};
  int e1 = 0; float p1 = p[0];
#pragma unroll
  for (int e = 1; e < 8; ++e) if (p[e] > p1) { p1 = p[e]; e1 = e; }
  int e2 = 0; float p2 = -1.f;
#pragma unroll
  for (int e = 0; e < 8; ++e) {
    if (e == e1) continue;
    if (p[e] > p2) { p2 = p[e]; e2 = e; }
  }
  float s = p1 + p2;
  size_t base = (size_t)t * NEXP * CAP;
  disp[base + (size_t)e1 * CAP + 0] = 1.f;
  comb[base + (size_t)e1 * CAP + 0] = p1 / s;
  int pos = expert_used[e2];
  disp[base + (size_t)e2 * CAP + pos] = 1.f;
  comb[base + (size_t)e2 * CAP + pos] = p2 / s;

  float mk = importance[t] > 0.5f ? 1.f : 0.f;
  float vals[16];
#pragma unroll
  for (int e = 0; e < 8; ++e) { vals[e] = p[e]; vals[8 + e] = p[e] * mk; }
#pragma unroll
  for (int k = 0; k < 16; ++k) {
    float v = vals[k];
    v += __shfl_xor(v, 1);  v += __shfl_xor(v, 2);  v += __shfl_xor(v, 4);
    v += __shfl_xor(v, 8);  v += __shfl_xor(v, 16); v += __shfl_xor(v, 32);
    vals[k] = v;
  }
  __shared__ float red[4][16];
  const int lane = tid & 63, wid = tid >> 6;
  if (lane == 0) {
#pragma unroll
    for (int k = 0; k < 16; ++k) red[wid][k] = vals[k];
  }
  __syncthreads();
  if (tid < 16)
    atomicAdd(&partials[tid],
              red[0][tid] + red[1][tid] + red[2][tid] + red[3][tid]);
}

// ---------------------------------------------------------------------------
__global__ __launch_bounds__(64)
void aux_final_k(float* __restrict__ partials, float* __restrict__ aux_out,
                 float* __restrict__ flag_tail) {
  const int tid = threadIdx.x;
  float s[16];
#pragma unroll
  for (int k = 0; k < 16; ++k) s[k] = partials[k];
  if (tid == 0) {
    float entropy_loss = 0.f;
#pragma unroll
    for (int e = 0; e < 8; ++e) {
      float rppe = s[e] / (float)M_TOK;
      entropy_loss += rppe * logf(rppe * 8.f + 1e-9f);
    }
    float tot = 0.f;
#pragma unroll
    for (int e = 0; e < 8; ++e) tot += s[8 + e] + 1e-9f;
    float imp_entropy = 0.f;
#pragma unroll
    for (int e = 0; e < 8; ++e) {
      float ipe = (s[8 + e] + 1e-9f) / tot;
      imp_entropy -= ipe * logf(ipe + 1e-9f);
    }
    aux_out[0] = entropy_loss - 0.1f * (imp_entropy / logf(8.f));
  }
  if (tid < 16) partials[tid] = 0.f;
  if (tid >= 16 && tid < 32) flag_tail[tid - 16] = 0.f;
}

// ---------------------------------------------------------------------------
extern "C" void kernel_launch(void* const* d_in, const int* in_sizes, int n_in,
                              void* d_out, int out_size, void* d_ws,
                              size_t ws_size, hipStream_t stream) {
  const float* x   = (const float*)d_in[0];
  const float* Wi1 = (const float*)d_in[1];
  const float* bi1 = (const float*)d_in[2];
  const float* Wi2 = (const float*)d_in[3];
  const float* bi2 = (const float*)d_in[4];
  const float* Wr1 = (const float*)d_in[5];
  const float* br1 = (const float*)d_in[6];
  const float* Wr2 = (const float*)d_in[7];
  const float* br2 = (const float*)d_in[8];
  const float* Wu1 = (const float*)d_in[9];
  const float* bu1 = (const float*)d_in[10];
  const float* Wu2 = (const float*)d_in[11];
  const float* bu2 = (const float*)d_in[12];

  float* out  = (float*)d_out;
  float* disp = out;
  float* comb = out + DISP_ELEMS;
  float* rp   = out + 2 * DISP_ELEMS;            // 32768
  float* aux  = out + 2 * DISP_ELEMS + 32768;    // 1
  float* imp  = aux + 1;                         // 4096

  const size_t xh_b  = (size_t)M_TOK * HID * 2;
  const size_t wT_b  = (size_t)NTOT * HID * 2;
  const size_t hi_b  = (size_t)M_TOK * 1024 * 4;
  const size_t hr_b  = (size_t)M_TOK * 2048 * 4;
  const size_t need  = 2 * xh_b + 2 * wT_b + hi_b + 2 * hr_b + 256;
  const bool ws_ok = (ws_size >= need);
  char* scratch = ws_ok ? (char*)d_ws : (char*)comb;

  unsigned short* xh  = (unsigned short*)scratch;
  unsigned short* xl  = (unsigned short*)(scratch + xh_b);
  unsigned short* wTh = (unsigned short*)(scratch + 2 * xh_b);
  unsigned short* wTl = (unsigned short*)(scratch + 2 * xh_b + wT_b);
  float* h_i = (float*)(scratch + 2 * xh_b + 2 * wT_b);
  float* h_r = h_i + (size_t)M_TOK * 1024;
  float* h_u = h_r + (size_t)M_TOK * 2048;
  int*   flags    = (int*)(comb + DISP_ELEMS - 16);
  float* partials = comb + DISP_ELEMS - 48;

  if (!ws_ok) {
    (void)hipMemsetAsync(disp, 0, DISP_ELEMS * sizeof(float), stream);
    (void)hipMemsetAsync(flags, 0, 16 * sizeof(float), stream);
  }

  // converts: x split + all three W^T splits (two launches, r10-proven)
  convert_x_k<<<(M_TOK * HID / 4) / 256, 256, 0, stream>>>(x, xh, xl);
  convert_wT_k<<<dim3(160, HID / 32), 256, 0, stream>>>(Wi1, Wr1, Wu1, wTh, wTl);

  // fused split-bf16 MFMA GEMM: 512 blocks = 2/CU, in-loop zerofill
  gemm_split_k<<<512, 512, 0, stream>>>(xh, xl, wTh, wTl, bi1, br1, bu1,
                                        h_i, h_r, h_u,
                                        ws_ok ? disp : (float*)nullptr);

  // router v2: 256 blocks x 16 tokens, W2 LDS-cached
  router_k<<<256, 256, 0, stream>>>(h_i, h_r, h_u, Wi2, bi2, Wr2, br2,
                                    Wu2, bu2, rp, imp, flags);

  if (!ws_ok)
    (void)hipMemsetAsync(comb, 0, (DISP_ELEMS - 16) * sizeof(float), stream);

  // scatter + aux partials
  scatter_aux_k<<<M_TOK / 256, 256, 0, stream>>>(rp, flags, imp, disp, comb,
                                                 partials);

  // aux finalize + zero partials/flag tail
  aux_final_k<<<1, 64, 0, stream>>>(partials, aux, (float*)flags);
}

// Round 13
// 292.377 us; speedup vs baseline: 1.0314x; 1.0314x over previous
//
#include <hip/hip_runtime.h>
#include <math.h>

#define M_TOK 4096           // B*S
#define HID   2048
#define NEXP  8
#define CAP   1536
#define DISP_ELEMS 50331648ull   // 4096*8*1536
#define NTOT  5120               // 1024 + 2048 + 2048 (concat N)
#define ZTOT4 25165824ull        // (2*DISP_ELEMS)/4 float4s

typedef __attribute__((ext_vector_type(8))) short bf16x8;
typedef __attribute__((ext_vector_type(4))) float f32x4;

__device__ __forceinline__ unsigned short f2bf(float f) {
  unsigned u = __float_as_uint(f);
  unsigned r = u + 0x7FFFu + ((u >> 16) & 1u);   // RNE (finite inputs)
  return (unsigned short)(r >> 16);
}
__device__ __forceinline__ float bf2f(unsigned short h) {
  return __uint_as_float(((unsigned)h) << 16);
}

__device__ __forceinline__ void gload16(const void* g, void* l) {
  __builtin_amdgcn_global_load_lds(
      (const __attribute__((address_space(1))) void*)g,
      (__attribute__((address_space(3))) void*)l, 16, 0, 0);
}
__device__ __forceinline__ bf16x8 ldsread(const unsigned short* p) {
  return *reinterpret_cast<const bf16x8*>(p);
}

// ---------------------------------------------------------------------------
// x (fp32 [M][K]) -> x_hi, x_lo (bf16 [M][K])   (r10-proven)
// ---------------------------------------------------------------------------
__global__ __launch_bounds__(256)
void convert_x_k(const float* __restrict__ x, unsigned short* __restrict__ xh,
                 unsigned short* __restrict__ xl) {
  size_t i = ((size_t)blockIdx.x * 256 + threadIdx.x) * 4;
  float4 v = *reinterpret_cast<const float4*>(&x[i]);
  float f[4] = {v.x, v.y, v.z, v.w};
  unsigned short hh[4], ll[4];
#pragma unroll
  for (int j = 0; j < 4; ++j) {
    hh[j] = f2bf(f[j]);
    ll[j] = f2bf(f[j] - bf2f(hh[j]));
  }
  uint2 ph, pl;
  ph.x = hh[0] | ((unsigned)hh[1] << 16); ph.y = hh[2] | ((unsigned)hh[3] << 16);
  pl.x = ll[0] | ((unsigned)ll[1] << 16); pl.y = ll[2] | ((unsigned)ll[3] << 16);
  *reinterpret_cast<uint2*>(&xh[i]) = ph;
  *reinterpret_cast<uint2*>(&xl[i]) = pl;
}

// ---------------------------------------------------------------------------
// All three W (fp32 [K=2048][N]) -> W^T hi/lo (bf16 [5120][2048]) (r10-proven)
// grid.x: 0..31 -> Wi1 (N=1024), 32..95 -> Wr1, 96..159 -> Wu1. grid.y = k0/32.
// ---------------------------------------------------------------------------
__global__ __launch_bounds__(256)
void convert_wT_k(const float* __restrict__ Wi1, const float* __restrict__ Wr1,
                  const float* __restrict__ Wu1,
                  unsigned short* __restrict__ wTh,
                  unsigned short* __restrict__ wTl) {
  __shared__ float tile[32][33];
  const int bx = blockIdx.x;
  const float* W; int N, rowOff, nb;
  if (bx < 32)      { W = Wi1; N = 1024; rowOff = 0;    nb = bx; }
  else if (bx < 96) { W = Wr1; N = 2048; rowOff = 1024; nb = bx - 32; }
  else              { W = Wu1; N = 2048; rowOff = 3072; nb = bx - 96; }
  const int k0 = blockIdx.y * 32;
  const int n0 = nb * 32;
  const int tid = threadIdx.x;
  {
    int r = tid >> 3, c4 = (tid & 7) * 4;
    float4 v = *reinterpret_cast<const float4*>(&W[(size_t)(k0 + r) * N + n0 + c4]);
    tile[r][c4 + 0] = v.x; tile[r][c4 + 1] = v.y;
    tile[r][c4 + 2] = v.z; tile[r][c4 + 3] = v.w;
  }
  __syncthreads();
  int n = tid >> 3, kc = (tid & 7) * 4;
  unsigned short hh[4], ll[4];
#pragma unroll
  for (int j = 0; j < 4; ++j) {
    float f = tile[kc + j][n];
    hh[j] = f2bf(f);
    ll[j] = f2bf(f - bf2f(hh[j]));
  }
  size_t o = (size_t)(rowOff + n0 + n) * HID + k0 + kc;
  uint2 ph, pl;
  ph.x = hh[0] | ((unsigned)hh[1] << 16); ph.y = hh[2] | ((unsigned)hh[3] << 16);
  pl.x = ll[0] | ((unsigned)ll[1] << 16); pl.y = ll[2] | ((unsigned)ll[3] << 16);
  *reinterpret_cast<uint2*>(&wTh[o]) = ph;
  *reinterpret_cast<uint2*>(&wTl[o]) = pl;
}

// ---------------------------------------------------------------------------
// Split-bf16 GEMM, single-generation geometry (r9/r10-proven BEST, 259 us):
//   C = relu(A@W + b), A = Ah+Al, B^T = Bh+Bl (bf16 splits)
//   C = Ah@Bh + Ah@Bl + Al@Bh   (fp32 accum; lo*lo dropped ~2^-18)
// BM=256, BN=320, BK=32 -> 16x16 = 256 blocks = EXACTLY 1 block/CU, 1 gen.
// 512 thr (8 waves 2M x 4N), wave-tile 128x80. LDS dbuf 2 x 72KB = 144 KB.
// Per K-tile: stage(t+1 -> other buf, 9 loads) | 3 zerofill nt-stores |
//   vmcnt(12) | barrier | computeTile(cur) | barrier
// Counted vmcnt (12 = 9 loads + 3 stores), never drained mid-loop.
// Zerofill of disp+comb (403MB): 256 blk x 64 t x 512 thr x 48B == exact.
// Slot-XOR swizzle both sides (PMC-verified 0 conflicts, r3).
// ---------------------------------------------------------------------------
__global__ __launch_bounds__(512, 2)
void gemm_split_k(const unsigned short* __restrict__ Ahg,
                  const unsigned short* __restrict__ Alg,
                  const unsigned short* __restrict__ Bhg,
                  const unsigned short* __restrict__ Blg,
                  const float* __restrict__ bi1, const float* __restrict__ br1,
                  const float* __restrict__ bu1, float* __restrict__ h_i,
                  float* __restrict__ h_r, float* __restrict__ h_u,
                  float* __restrict__ dzero) {
  // per-buffer layout (shorts): Ah@0(8192) Al@8192 Bh@16384(10240) Bl@26624
  __shared__ unsigned short lds[73728];          // 2 x 36864 shorts = 144 KB
  const int bid  = blockIdx.x;
  const int tid  = threadIdx.x;
  const int lane = tid & 63;
  const int wave = tid >> 6;
  const int lr   = lane & 15;
  const int slot = lane >> 4;                    // k-slot 0..3

  // XCD swizzle: xcd = bid&7 gets a 2-M-stripe x 16-N (B panel L2-shared)
  const int idx = bid >> 3;                      // 0..31
  const int mt  = ((bid & 7) << 1) | (idx >> 4); // 0..15
  const int nt  = idx & 15;                      // 0..15
  const int row0  = mt * 256;
  const int bcol0 = nt * 320;

  // ---- staging map: 9 x 16B chunks per thread per K-tile (72KB total)
  const unsigned short* gsrc[9];
#pragma unroll
  for (int j = 0; j < 9; ++j) {
    int c = (wave * 9 + j) * 64 + lane;
    const unsigned short* base;
    int sidx, rowg;
    if (c < 2048) {                              // A hi/lo: 256 rows x 4 slots
      sidx = c & 1023;
      base = (c < 1024) ? Ahg : Alg;
      rowg = row0 + (sidx >> 2);
    } else {                                     // B hi/lo: 320 rows x 4 slots
      sidx = (c < 3328) ? (c - 2048) : (c - 3328);
      base = (c < 3328) ? Bhg : Blg;
      rowg = bcol0 + (sidx >> 2);
    }
    int q  = sidx & 3;
    int qs = q ^ (((sidx >> 2) >> 1) & 3);       // pre-swizzled source slot
    gsrc[j] = base + (size_t)rowg * HID + qs * 8;
  }
  const int ldsbase = wave * 4608 + lane * 8;    // linear LDS dest (shorts)

  // ---- ds_read offsets (swizzled, conflict-free)
  int aoff[8], boff[5];
#pragma unroll
  for (int m = 0; m < 8; ++m) {
    int ra = (wave >> 2) * 128 + m * 16 + lr;    // 0..255
    aoff[m] = ra * 32 + (slot ^ ((ra >> 1) & 3)) * 8;
  }
#pragma unroll
  for (int n = 0; n < 5; ++n) {
    int rb = (wave & 3) * 80 + n * 16 + lr;      // 0..319
    boff[n] = rb * 32 + (slot ^ ((rb >> 1) & 3)) * 8;
  }

  f32x4 acc[8][5];
#pragma unroll
  for (int m = 0; m < 8; ++m)
#pragma unroll
    for (int n = 0; n < 5; ++n) acc[m][n] = (f32x4){0.f, 0.f, 0.f, 0.f};

  auto stage = [&](int kt, unsigned short* buf) {
#pragma unroll
    for (int j = 0; j < 9; ++j)
      gload16(gsrc[j] + kt * 32, buf + ldsbase + j * 512);
  };
  auto computeTile = [&](const unsigned short* bb) {
    bf16x8 bvh[5], bvl[5];
#pragma unroll
    for (int n = 0; n < 5; ++n) {
      bvh[n] = ldsread(&bb[16384 + boff[n]]);
      bvl[n] = ldsread(&bb[26624 + boff[n]]);
    }
#pragma unroll
    for (int m = 0; m < 8; ++m) {
      bf16x8 ah = ldsread(&bb[aoff[m]]);
      bf16x8 al = ldsread(&bb[8192 + aoff[m]]);
      __builtin_amdgcn_s_setprio(1);
#pragma unroll
      for (int n = 0; n < 5; ++n) {
        acc[m][n] = __builtin_amdgcn_mfma_f32_16x16x32_bf16(ah, bvh[n], acc[m][n], 0, 0, 0);
        acc[m][n] = __builtin_amdgcn_mfma_f32_16x16x32_bf16(ah, bvl[n], acc[m][n], 0, 0, 0);
        acc[m][n] = __builtin_amdgcn_mfma_f32_16x16x32_bf16(al, bvh[n], acc[m][n], 0, 0, 0);
      }
      __builtin_amdgcn_s_setprio(0);
    }
  };

  unsigned short* b0 = &lds[0];
  unsigned short* b1 = &lds[36864];
  const bool dz = (dzero != nullptr);
  f32x4* d4 = (f32x4*)dzero;
  const f32x4 zv = (f32x4){0.f, 0.f, 0.f, 0.f};

  stage(0, b0);                                  // prologue: tile 0 in flight

#pragma unroll 1
  for (int t = 0; t < 64; ++t) {
    unsigned short* cur = (t & 1) ? b1 : b0;
    unsigned short* nxt = (t & 1) ? b0 : b1;
    if (t < 63) stage(t + 1, nxt);               // 9 loads, early issue
    if (dz) {                                    // 3 coalesced nt-stores
      size_t zb = ((size_t)(bid * 64 + t) * 3) * 512 + tid;
      __builtin_nontemporal_store(zv, d4 + zb);
      __builtin_nontemporal_store(zv, d4 + zb + 512);
      __builtin_nontemporal_store(zv, d4 + zb + 1024);
    }
    // wait: tile t's 9 loads landed (newest 12/9/3/0 may stay in flight)
    if (t < 63) {
      if (dz) asm volatile("s_waitcnt vmcnt(12)" ::: "memory");
      else    asm volatile("s_waitcnt vmcnt(9)"  ::: "memory");
    } else {
      if (dz) asm volatile("s_waitcnt vmcnt(3)"  ::: "memory");
      else    asm volatile("s_waitcnt vmcnt(0)"  ::: "memory");
    }
    __builtin_amdgcn_s_barrier();                // all waves' t-loads in LDS
    __builtin_amdgcn_sched_barrier(0);
    computeTile(cur);
    __builtin_amdgcn_s_barrier();                // cur free for stage(t+2)
  }

  // ---- epilogue: bias + relu + store (wave-uniform 3-way select per frag)
#pragma unroll
  for (int n = 0; n < 5; ++n) {
    int cbase = nt * 320 + (wave & 3) * 80 + n * 16;
    float* C; const float* bias; int ldc, coff;
    if (cbase < 1024)      { C = h_i; bias = bi1; ldc = 1024; coff = 0; }
    else if (cbase < 3072) { C = h_r; bias = br1; ldc = 2048; coff = 1024; }
    else                   { C = h_u; bias = bu1; ldc = 2048; coff = 3072; }
    int cl = cbase - coff + lr;
    float bn = bias[cl];
#pragma unroll
    for (int m = 0; m < 8; ++m) {
      int rbase = row0 + (wave >> 2) * 128 + m * 16 + slot * 4;
#pragma unroll
      for (int j = 0; j < 4; ++j)
        C[(size_t)(rbase + j) * ldc + cl] = fmaxf(acc[m][n][j] + bn, 0.f);
    }
  }
}

// ---------------------------------------------------------------------------
// Router v2 (r10-proven): 256 blocks x 16 tokens, W2 staged once into LDS.
// ---------------------------------------------------------------------------
__global__ __launch_bounds__(256)
void router_k(const float* __restrict__ h_i, const float* __restrict__ h_r,
              const float* __restrict__ h_u,
              const float* __restrict__ Wi2, const float* __restrict__ bi2,
              const float* __restrict__ Wr2, const float* __restrict__ br2,
              const float* __restrict__ Wu2, const float* __restrict__ bu2,
              float* __restrict__ router_probs, float* __restrict__ importance,
              int* __restrict__ expert_used) {
  __shared__ float wr[18432];   // 2048 rows x 9 (8 used + pad)
  __shared__ float wu[18432];
  __shared__ float wi[1024];
  const int tid = threadIdx.x;

  for (int idx = tid; idx < 16384; idx += 256)
    wr[(idx >> 3) * 9 + (idx & 7)] = Wr2[idx];
  for (int idx = tid; idx < 16384; idx += 256)
    wu[(idx >> 3) * 9 + (idx & 7)] = Wu2[idx];
  for (int idx = tid; idx < 1024; idx += 256) wi[idx] = Wi2[idx];
  __syncthreads();

  const int w = tid >> 6, l = tid & 63;
  const float bi2v = bi2[0];

#pragma unroll 1
  for (int tt = 0; tt < 4; ++tt) {
    const int t = blockIdx.x * 16 + tt * 4 + w;
    float acc[17];
#pragma unroll
    for (int k = 0; k < 17; ++k) acc[k] = 0.f;

    const float* hi = &h_i[(size_t)t * 1024];
    const float* hr = &h_r[(size_t)t * 2048];
    const float* hu = &h_u[(size_t)t * 2048];
#pragma unroll 4
    for (int j = 0; j < 16; ++j) {
      int k = j * 64 + l;
      acc[0] = fmaf(hi[k], wi[k], acc[0]);
    }
#pragma unroll 4
    for (int j = 0; j < 32; ++j) {
      int k = j * 64 + l;
      float hrv = hr[k], huv = hu[k];
      const float* wrr = &wr[k * 9];
      const float* wuu = &wu[k * 9];
#pragma unroll
      for (int e = 0; e < 8; ++e) {
        acc[1 + e] = fmaf(hrv, wrr[e], acc[1 + e]);
        acc[9 + e] = fmaf(huv, wuu[e], acc[9 + e]);
      }
    }
#pragma unroll
    for (int k = 0; k < 17; ++k) {
      float v = acc[k];
      v += __shfl_xor(v, 1);  v += __shfl_xor(v, 2);  v += __shfl_xor(v, 4);
      v += __shfl_xor(v, 8);  v += __shfl_xor(v, 16); v += __shfl_xor(v, 32);
      acc[k] = v;
    }
    if (l == 0) {
      float imp = 1.f / (1.f + expf(-(acc[0] + bi2v)));
      importance[t] = imp;
      bool useImp = imp > 0.5f;
      float logits[8];
#pragma unroll
      for (int e = 0; e < 8; ++e)
        logits[e] = useImp ? (acc[1 + e] + br2[e]) : (acc[9 + e] + bu2[e]);
      float mx = logits[0];
#pragma unroll
      for (int e = 1; e < 8; ++e) mx = fmaxf(mx, logits[e]);
      float ex[8], sum = 0.f;
#pragma unroll
      for (int e = 0; e < 8; ++e) { ex[e] = expf(logits[e] - mx); sum += ex[e]; }
      float p[8];
#pragma unroll
      for (int e = 0; e < 8; ++e) p[e] = ex[e] / sum;
#pragma unroll
      for (int e = 0; e < 8; ++e) router_probs[(size_t)t * 8 + e] = p[e];
      int e1 = 0; float p1 = p[0];
#pragma unroll
      for (int e = 1; e < 8; ++e) if (p[e] > p1) { p1 = p[e]; e1 = e; }
      expert_used[e1] = 1;   // benign race: all writers store 1
    }
  }
}

// ---------------------------------------------------------------------------
// Scatter + aux partial reduction. 16 blocks x 256 thr.
// ---------------------------------------------------------------------------
__global__ __launch_bounds__(256)
void scatter_aux_k(const float* __restrict__ router_probs,
                   const int* __restrict__ expert_used,
                   const float* __restrict__ importance,
                   float* __restrict__ disp, float* __restrict__ comb,
                   float* __restrict__ partials) {
  const int tid = threadIdx.x;
  const int t = blockIdx.x * 256 + tid;
  float4 a = *reinterpret_cast<const float4*>(&router_probs[(size_t)t * 8]);
  float4 b = *reinterpret_cast<const float4*>(&router_probs[(size_t)t * 8 + 4]);
  float p[8] = {a.x, a.y, a.z, a.w, b.x, b.y, b.z, b.w};
  int e1 = 0; float p1 = p[0];
#pragma unroll
  for (int e = 1; e < 8; ++e) if (p[e] > p1) { p1 = p[e]; e1 = e; }
  int e2 = 0; float p2 = -1.f;
#pragma unroll
  for (int e = 0; e < 8; ++e) {
    if (e == e1) continue;
    if (p[e] > p2) { p2 = p[e]; e2 = e; }
  }
  float s = p1 + p2;
  size_t base = (size_t)t * NEXP * CAP;
  disp[base + (size_t)e1 * CAP + 0] = 1.f;
  comb[base + (size_t)e1 * CAP + 0] = p1 / s;
  int pos = expert_used[e2];
  disp[base + (size_t)e2 * CAP + pos] = 1.f;
  comb[base + (size_t)e2 * CAP + pos] = p2 / s;

  float mk = importance[t] > 0.5f ? 1.f : 0.f;
  float vals[16];
#pragma unroll
  for (int e = 0; e < 8; ++e) { vals[e] = p[e]; vals[8 + e] = p[e] * mk; }
#pragma unroll
  for (int k = 0; k < 16; ++k) {
    float v = vals[k];
    v += __shfl_xor(v, 1);  v += __shfl_xor(v, 2);  v += __shfl_xor(v, 4);
    v += __shfl_xor(v, 8);  v += __shfl_xor(v, 16); v += __shfl_xor(v, 32);
    vals[k] = v;
  }
  __shared__ float red[4][16];
  const int lane = tid & 63, wid = tid >> 6;
  if (lane == 0) {
#pragma unroll
    for (int k = 0; k < 16; ++k) red[wid][k] = vals[k];
  }
  __syncthreads();
  if (tid < 16)
    atomicAdd(&partials[tid],
              red[0][tid] + red[1][tid] + red[2][tid] + red[3][tid]);
}

// ---------------------------------------------------------------------------
__global__ __launch_bounds__(64)
void aux_final_k(float* __restrict__ partials, float* __restrict__ aux_out,
                 float* __restrict__ flag_tail) {
  const int tid = threadIdx.x;
  float s[16];
#pragma unroll
  for (int k = 0; k < 16; ++k) s[k] = partials[k];
  if (tid == 0) {
    float entropy_loss = 0.f;
#pragma unroll
    for (int e = 0; e < 8; ++e) {
      float rppe = s[e] / (float)M_TOK;
      entropy_loss += rppe * logf(rppe * 8.f + 1e-9f);
    }
    float tot = 0.f;
#pragma unroll
    for (int e = 0; e < 8; ++e) tot += s[8 + e] + 1e-9f;
    float imp_entropy = 0.f;
#pragma unroll
    for (int e = 0; e < 8; ++e) {
      float ipe = (s[8 + e] + 1e-9f) / tot;
      imp_entropy -= ipe * logf(ipe + 1e-9f);
    }
    aux_out[0] = entropy_loss - 0.1f * (imp_entropy / logf(8.f));
  }
  if (tid < 16) partials[tid] = 0.f;
  if (tid >= 16 && tid < 32) flag_tail[tid - 16] = 0.f;
}

// ---------------------------------------------------------------------------
extern "C" void kernel_launch(void* const* d_in, const int* in_sizes, int n_in,
                              void* d_out, int out_size, void* d_ws,
                              size_t ws_size, hipStream_t stream) {
  const float* x   = (const float*)d_in[0];
  const float* Wi1 = (const float*)d_in[1];
  const float* bi1 = (const float*)d_in[2];
  const float* Wi2 = (const float*)d_in[3];
  const float* bi2 = (const float*)d_in[4];
  const float* Wr1 = (const float*)d_in[5];
  const float* br1 = (const float*)d_in[6];
  const float* Wr2 = (const float*)d_in[7];
  const float* br2 = (const float*)d_in[8];
  const float* Wu1 = (const float*)d_in[9];
  const float* bu1 = (const float*)d_in[10];
  const float* Wu2 = (const float*)d_in[11];
  const float* bu2 = (const float*)d_in[12];

  float* out  = (float*)d_out;
  float* disp = out;
  float* comb = out + DISP_ELEMS;
  float* rp   = out + 2 * DISP_ELEMS;            // 32768
  float* aux  = out + 2 * DISP_ELEMS + 32768;    // 1
  float* imp  = aux + 1;                         // 4096

  const size_t xh_b  = (size_t)M_TOK * HID * 2;
  const size_t wT_b  = (size_t)NTOT * HID * 2;
  const size_t hi_b  = (size_t)M_TOK * 1024 * 4;
  const size_t hr_b  = (size_t)M_TOK * 2048 * 4;
  const size_t need  = 2 * xh_b + 2 * wT_b + hi_b + 2 * hr_b + 256;
  const bool ws_ok = (ws_size >= need);
  char* scratch = ws_ok ? (char*)d_ws : (char*)comb;

  unsigned short* xh  = (unsigned short*)scratch;
  unsigned short* xl  = (unsigned short*)(scratch + xh_b);
  unsigned short* wTh = (unsigned short*)(scratch + 2 * xh_b);
  unsigned short* wTl = (unsigned short*)(scratch + 2 * xh_b + wT_b);
  float* h_i = (float*)(scratch + 2 * xh_b + 2 * wT_b);
  float* h_r = h_i + (size_t)M_TOK * 1024;
  float* h_u = h_r + (size_t)M_TOK * 2048;
  int*   flags    = (int*)(comb + DISP_ELEMS - 16);
  float* partials = comb + DISP_ELEMS - 48;

  if (!ws_ok) {
    (void)hipMemsetAsync(disp, 0, DISP_ELEMS * sizeof(float), stream);
    (void)hipMemsetAsync(flags, 0, 16 * sizeof(float), stream);
  }

  // converts: x split + all three W^T splits (two launches, r10-proven)
  convert_x_k<<<(M_TOK * HID / 4) / 256, 256, 0, stream>>>(x, xh, xl);
  convert_wT_k<<<dim3(160, HID / 32), 256, 0, stream>>>(Wi1, Wr1, Wu1, wTh, wTl);

  // fused split-bf16 MFMA GEMM: 256 blocks = 1/CU, in-loop zerofill
  gemm_split_k<<<256, 512, 0, stream>>>(xh, xl, wTh, wTl, bi1, br1, bu1,
                                        h_i, h_r, h_u,
                                        ws_ok ? disp : (float*)nullptr);

  // router v2: 256 blocks x 16 tokens, W2 LDS-cached
  router_k<<<256, 256, 0, stream>>>(h_i, h_r, h_u, Wi2, bi2, Wr2, br2,
                                    Wu2, bu2, rp, imp, flags);

  if (!ws_ok)
    (void)hipMemsetAsync(comb, 0, (DISP_ELEMS - 16) * sizeof(float), stream);

  // scatter + aux partials
  scatter_aux_k<<<M_TOK / 256, 256, 0, stream>>>(rp, flags, imp, disp, comb,
                                                 partials);

  // aux finalize + zero partials/flag tail
  aux_final_k<<<1, 64, 0, stream>>>(partials, aux, (float*)flags);
}